// Round 7
// baseline (142.841 us; speedup 1.0000x reference)
//
#include <hip/hip_runtime.h>

#define BS 4
#define NQ 16384

typedef unsigned short u16;
typedef unsigned int u32;
typedef unsigned char u8;
typedef __attribute__((ext_vector_type(8))) short bf16x8;   // 8 bf16 (4 VGPRs)
typedef __attribute__((ext_vector_type(4))) short bf16x4;
typedef __attribute__((ext_vector_type(4))) float f32x4;
typedef __attribute__((ext_vector_type(2))) float f32x2;

__device__ __forceinline__ float bf2f(u16 v) { return __uint_as_float(((u32)v) << 16); }
__device__ __forceinline__ u16 f2bf(float f) {           // RNE (setup only, cold)
    u32 u = __float_as_uint(f);
    return (u16)((u + 0x7fffu + ((u >> 16) & 1u)) >> 16);
}
// pack two f32 -> two bf16 (truncation) in ONE v_perm_b32
__device__ __forceinline__ u32 pk_trunc(float lo, float hi) {
    return __builtin_amdgcn_perm(__float_as_uint(hi), __float_as_uint(lo), 0x07060302u);
}

union ABu { bf16x8 v; u32 u[4]; };

__device__ __forceinline__ void load8(f32x4* buf, const float* p) {
    #pragma unroll
    for (int kb = 0; kb < 4; ++kb) {
        buf[2 * kb]     = *(const f32x4*)(p + kb * 32);
        buf[2 * kb + 1] = *(const f32x4*)(p + kb * 32 + 4);
    }
}
__device__ __forceinline__ void cvt_frag(const f32x4* buf, bf16x8* frag) {
    #pragma unroll
    for (int kb = 0; kb < 4; ++kb) {
        ABu ab;
        ab.u[0] = pk_trunc(buf[2 * kb].x,     buf[2 * kb].y);
        ab.u[1] = pk_trunc(buf[2 * kb].z,     buf[2 * kb].w);
        ab.u[2] = pk_trunc(buf[2 * kb + 1].x, buf[2 * kb + 1].y);
        ab.u[3] = pk_trunc(buf[2 * kb + 1].z, buf[2 * kb + 1].w);
        frag[kb] = ab.v;
    }
}

// ---------------------------------------------------------------------------
// Setup: swizzle weights into MFMA fragment order (bf16, RNE).
// frag: f[j] = W[k = kb*32 + quad*8 + j][n = nt*16 + lane16], flat index
// (((nt*4+kb)*4+quad)*16 + lane16)*8 + j. Serves as B-frag (n=col) or as
// A-frag of W^T (m=col) — identical layout.
// ---------------------------------------------------------------------------
__global__ __launch_bounds__(256)
void setup_kernel(const float* __restrict__ W_val, const float* __restrict__ W_off,
                  const float* __restrict__ W_attn, const float* __restrict__ W_out,
                  u16* __restrict__ Wswz, u16* __restrict__ Wout_swz)
{
    const int i = blockIdx.x * 256 + threadIdx.x;
    if (i < 28672) {                       // proj [W_val | W_off | W_attn], 14 nt
        const int j = i & 7, lane = (i >> 3) & 15, quad = (i >> 7) & 3;
        const int kb = (i >> 9) & 3, nt = i >> 11;
        const int k = kb * 32 + quad * 8 + j;
        const int n = nt * 16 + lane;
        float v;
        if (n < 128)      v = W_val[k * 128 + n];
        else if (n < 192) v = W_off[k * 64 + (n - 128)];
        else              v = W_attn[k * 32 + (n - 192)];
        Wswz[i] = f2bf(v);
    } else if (i < 45056) {                // W_out, 8 nt
        const int i2 = i - 28672;
        const int j = i2 & 7, lane = (i2 >> 3) & 15, quad = (i2 >> 7) & 3;
        const int kb = (i2 >> 9) & 3, nt = i2 >> 11;
        const int k = kb * 32 + quad * 8 + j;
        const int n = nt * 16 + lane;
        Wout_swz[i2] = f2bf(W_out[k * 128 + n]);
    }
}

// ---------------------------------------------------------------------------
// Fused kernel (structure = R6 + XCD swizzle + phase-1 MLP + epilogue prefetch):
//   block = 8x8 token square, 12x12 fp8 value halo in LDS.
//   1: off/attn proj (swapped MFMA) -> scratch; fp8 value halo (9 tiles,
//      swapped MFMA, D=[dim][pixel]) -> vhalo. All global query loads for
//      own + 2 halo tiles issued up front (24 dwordx4 in flight).
//   2a: off/attn -> regs, softmax          [barrier frees scratch]
//   2b: epilogue-query prefetch, then bilinear gather (ds_read_b128 + HW fp8
//       unpack) -> s tile
//   2c: out MFMA + bias + 2*query residual (prefetched), nontemporal stores.
// XCD swizzle: bid&7 = XCD -> each XCD owns a contiguous half-batch region
// (8x16 squares = ~4 MB query) for L2 locality. Perf-only heuristic.
// C/D layout: col = lane&15, row = quad*4 + reg  [measured m89].
// ---------------------------------------------------------------------------
__global__ __launch_bounds__(256, 3)
void fused_kernel(const float* __restrict__ query,
                  const float* __restrict__ b_off, const float* __restrict__ b_attn,
                  const float* __restrict__ b_val, const float* __restrict__ b_out,
                  const u16* __restrict__ Wswz, const u16* __restrict__ Wout_swz,
                  float* __restrict__ out)
{
    __shared__ __align__(16) u8  vhalo[144 * 144];   // 20736 B, row stride 144 B
    __shared__ __align__(16) u16 scratch[64 * 136];  // 17408 B (off/attn, then s)

    const int tid = threadIdx.x;
    const int bid = blockIdx.x;
    // XCD-aware swizzle: xcd = bid&7 gets a contiguous 8x16-square half-batch
    const int xcd = bid & 7;
    const int ii  = bid >> 3;                 // 0..127 within the XCD's region
    const int b_  = xcd >> 1;                 // batch 0..3
    const int Y   = (((xcd & 1) << 3) | (ii >> 4)) << 3;   // 0..120
    const int X   = (ii & 15) << 3;

    const int w = tid >> 6, l = tid & 63;
    const int lane16 = l & 15, quad = l >> 4;
    const size_t batch_base = (size_t)b_ * NQ;

    const bf16x8* Wf  = (const bf16x8*)Wswz;
    const bf16x8* WfO = (const bf16x8*)Wout_swz;

    // ---------------- phase 1: issue loads, then process --------------------
    {
        const int tl = w * 16 + lane16;              // own token (lane = token)
        const float* qp_own = query +
            (batch_base + (size_t)(Y + (tl >> 3)) * 128 + (X + (tl & 7))) * 128 + quad * 8;

        // halo row pointers for tiles a1 = w, a2 = 4+w (and 8 for wave 0)
        const int a1 = w, a2 = 4 + w;
        const float* qp1;
        const float* qp2;
        const float* qp3;
        {
            int hp = a1 * 16 + lane16;
            int hy = hp / 12, hx = hp - hy * 12;
            qp1 = query + (batch_base +
                  (size_t)min(max(Y - 2 + hy, 0), 127) * 128 +
                  min(max(X - 2 + hx, 0), 127)) * 128 + quad * 8;
            hp = a2 * 16 + lane16;
            hy = hp / 12; hx = hp - hy * 12;
            qp2 = query + (batch_base +
                  (size_t)min(max(Y - 2 + hy, 0), 127) * 128 +
                  min(max(X - 2 + hx, 0), 127)) * 128 + quad * 8;
            hp = 8 * 16 + lane16;
            hy = hp / 12; hx = hp - hy * 12;
            qp3 = query + (batch_base +
                  (size_t)min(max(Y - 2 + hy, 0), 127) * 128 +
                  min(max(X - 2 + hx, 0), 127)) * 128 + quad * 8;
        }

        f32x4 A[8], B[8], C[8], D[8];
        load8(A, qp_own);                    // 24 dwordx4 in flight together
        load8(B, qp1);
        load8(C, qp2);

        bf16x8 qf[4];
        // ---- own tokens: off/attn (swapped operands, D = [col][token]) ----
        cvt_frag(A, qf);
        #pragma unroll
        for (int ntile = 0; ntile < 6; ++ntile) {
            const int nt = 8 + ntile;
            f32x4 acc = {0.f, 0.f, 0.f, 0.f};
            const bf16x8* wp = Wf + ((size_t)(nt * 4) * 4 + quad) * 16 + lane16;
            #pragma unroll
            for (int kb = 0; kb < 4; ++kb)
                acc = __builtin_amdgcn_mfma_f32_16x16x32_bf16(wp[kb * 64], qf[kb], acc, 0, 0, 0);
            const int c = ntile * 16 + quad * 4;     // col 0..95
            const float4 bias = (ntile < 4) ? *(const float4*)&b_off[c]
                                            : *(const float4*)&b_attn[c - 64];
            uint2 pk;
            pk.x = pk_trunc(acc[0] + bias.x, acc[1] + bias.y);
            pk.y = pk_trunc(acc[2] + bias.z, acc[3] + bias.w);
            *(uint2*)&scratch[tl * 96 + c] = pk;
        }
        if (w == 0) load8(D, qp3);           // wave 0's extra tile, issued early

        // ---- halo tiles: value proj, fp8 store (D = [dim][pixel]) ----
        #pragma unroll
        for (int tsel = 0; tsel < 2; ++tsel) {
            cvt_frag(tsel ? C : B, qf);
            const int hp = (tsel ? a2 : a1) * 16 + lane16;   // pixel (lane = pixel)
            #pragma unroll
            for (int mt = 0; mt < 8; ++mt) {
                f32x4 acc = {0.f, 0.f, 0.f, 0.f};
                const bf16x8* wp = Wf + ((size_t)(mt * 4) * 4 + quad) * 16 + lane16;
                #pragma unroll
                for (int kb = 0; kb < 4; ++kb)
                    acc = __builtin_amdgcn_mfma_f32_16x16x32_bf16(wp[kb * 64], qf[kb], acc, 0, 0, 0);
                const int d0 = mt * 16 + quad * 4;
                const float4 bias = *(const float4*)&b_val[d0];
                u32 pk = __builtin_amdgcn_cvt_pk_fp8_f32(acc[0] + bias.x, acc[1] + bias.y, 0, false);
                pk     = __builtin_amdgcn_cvt_pk_fp8_f32(acc[2] + bias.z, acc[3] + bias.w, pk, true);
                *(u32*)&vhalo[hp * 144 + d0] = pk;
            }
        }
        if (w == 0) {                        // tile 8 (wave-uniform branch)
            cvt_frag(D, qf);
            const int hp = 8 * 16 + lane16;
            #pragma unroll
            for (int mt = 0; mt < 8; ++mt) {
                f32x4 acc = {0.f, 0.f, 0.f, 0.f};
                const bf16x8* wp = Wf + ((size_t)(mt * 4) * 4 + quad) * 16 + lane16;
                #pragma unroll
                for (int kb = 0; kb < 4; ++kb)
                    acc = __builtin_amdgcn_mfma_f32_16x16x32_bf16(wp[kb * 64], qf[kb], acc, 0, 0, 0);
                const int d0 = mt * 16 + quad * 4;
                const float4 bias = *(const float4*)&b_val[d0];
                u32 pk = __builtin_amdgcn_cvt_pk_fp8_f32(acc[0] + bias.x, acc[1] + bias.y, 0, false);
                pk     = __builtin_amdgcn_cvt_pk_fp8_f32(acc[2] + bias.z, acc[3] + bias.w, pk, true);
                *(u32*)&vhalo[hp * 144 + d0] = pk;
            }
        }
    }
    __syncthreads();

    // ---------------- 2a: off/attn -> regs (softmax over 4 pts) ---------------
    float aw[2][4], ox[2][4], oy[2][4];
    #pragma unroll
    for (int it = 0; it < 2; ++it) {
        const int item = it * 256 + tid;
        const int t = item >> 3, h = item & 7;
        bf16x8 ofr = *(const bf16x8*)&scratch[t * 96 + h * 8];
        bf16x4 atr = *(const bf16x4*)&scratch[t * 96 + 64 + h * 4];
        #pragma unroll
        for (int p = 0; p < 4; ++p) {
            ox[it][p] = bf2f((u16)ofr[2 * p]);
            oy[it][p] = bf2f((u16)ofr[2 * p + 1]);
        }
        const float l0 = bf2f((u16)atr[0]), l1 = bf2f((u16)atr[1]);
        const float l2 = bf2f((u16)atr[2]), l3 = bf2f((u16)atr[3]);
        const float m = fmaxf(fmaxf(l0, l1), fmaxf(l2, l3));
        const float e0 = __expf(l0 - m), e1 = __expf(l1 - m);
        const float e2 = __expf(l2 - m), e3 = __expf(l3 - m);
        const float inv = 1.0f / (e0 + e1 + e2 + e3);
        aw[it][0] = e0 * inv; aw[it][1] = e1 * inv;
        aw[it][2] = e2 * inv; aw[it][3] = e3 * inv;
    }
    __syncthreads();   // scratch becomes the s tile

    // ---------------- 2b: epilogue-query prefetch + gather -> s tile ----------
    float qpre[8][4];                        // q[token quad*4+r][nt*16+lane16]
    #pragma unroll
    for (int r = 0; r < 4; ++r) {
        const int tl = w * 16 + quad * 4 + r;
        const float* qp = query +
            (batch_base + (size_t)(Y + (tl >> 3)) * 128 + (X + (tl & 7))) * 128 + lane16;
        #pragma unroll
        for (int nt = 0; nt < 8; ++nt)
            qpre[nt][r] = qp[nt * 16];
    }

    #pragma unroll
    for (int it = 0; it < 2; ++it) {
        const int item = it * 256 + tid;
        const int t = item >> 3, h = item & 7;
        const int qx = X + (t & 7), qy = Y + (t >> 3);
        const float cx = (float)qx * (128.0f / 127.0f);
        const float cy = (float)qy * (128.0f / 127.0f);

        f32x2 acc2[8];
        #pragma unroll
        for (int d = 0; d < 8; ++d) acc2[d] = (f32x2){0.f, 0.f};

        #pragma unroll
        for (int p = 0; p < 4; ++p) {
            const float px = cx + ox[it][p] - 0.5f;
            const float py = cy + oy[it][p] - 0.5f;
            const float fx = floorf(px), fy = floorf(py);
            const float wx = px - fx, wy = py - fy;
            const int xi = (int)fx, yi = (int)fy;
            const float cw[4] = {(1.f - wx) * (1.f - wy), wx * (1.f - wy),
                                 (1.f - wx) * wy,         wx * wy};
            const int hx0 = min(max(xi - X + 2, 0), 11), hx1 = min(hx0 + 1, 11);
            const int hy0 = min(max(yi - Y + 2, 0), 11), hy1 = min(hy0 + 1, 11);
            const int cxs[4] = {hx0, hx1, hx0, hx1};
            const int cys[4] = {hy0, hy0, hy1, hy1};
            const int gxs[4] = {xi, xi + 1, xi, xi + 1};
            const int gys[4] = {yi, yi, yi + 1, yi + 1};
            #pragma unroll
            for (int c4 = 0; c4 < 4; ++c4) {
                const bool valid = (gxs[c4] >= 0) & (gxs[c4] < 128) &
                                   (gys[c4] >= 0) & (gys[c4] < 128);
                const float wgt = valid ? cw[c4] * aw[it][p] : 0.f;
                const f32x2 w2 = {wgt, wgt};
                const int hp = cys[c4] * 12 + cxs[c4];
                const int4 rv = *(const int4*)&vhalo[hp * 144 + h * 16];
                acc2[0] += w2 * __builtin_amdgcn_cvt_pk_f32_fp8(rv.x, false);
                acc2[1] += w2 * __builtin_amdgcn_cvt_pk_f32_fp8(rv.x, true);
                acc2[2] += w2 * __builtin_amdgcn_cvt_pk_f32_fp8(rv.y, false);
                acc2[3] += w2 * __builtin_amdgcn_cvt_pk_f32_fp8(rv.y, true);
                acc2[4] += w2 * __builtin_amdgcn_cvt_pk_f32_fp8(rv.z, false);
                acc2[5] += w2 * __builtin_amdgcn_cvt_pk_f32_fp8(rv.z, true);
                acc2[6] += w2 * __builtin_amdgcn_cvt_pk_f32_fp8(rv.w, false);
                acc2[7] += w2 * __builtin_amdgcn_cvt_pk_f32_fp8(rv.w, true);
            }
        }
        uint4 s0, s1;
        s0.x = pk_trunc(acc2[0][0], acc2[0][1]); s0.y = pk_trunc(acc2[1][0], acc2[1][1]);
        s0.z = pk_trunc(acc2[2][0], acc2[2][1]); s0.w = pk_trunc(acc2[3][0], acc2[3][1]);
        s1.x = pk_trunc(acc2[4][0], acc2[4][1]); s1.y = pk_trunc(acc2[5][0], acc2[5][1]);
        s1.z = pk_trunc(acc2[6][0], acc2[6][1]); s1.w = pk_trunc(acc2[7][0], acc2[7][1]);
        *(uint4*)&scratch[t * 136 + h * 16]     = s0;
        *(uint4*)&scratch[t * 136 + h * 16 + 8] = s1;
    }
    __syncthreads();

    // ---------------- 2c: out MFMA (normal orientation) + residual ------------
    {
        bf16x8 afrag[4];
        #pragma unroll
        for (int kb = 0; kb < 4; ++kb)
            afrag[kb] = *(const bf16x8*)&scratch[(w * 16 + lane16) * 136 + kb * 32 + quad * 8];

        #pragma unroll
        for (int nt = 0; nt < 8; ++nt) {
            f32x4 acc = {0.f, 0.f, 0.f, 0.f};
            const bf16x8* bp = WfO + ((size_t)(nt * 4) * 4 + quad) * 16 + lane16;
            #pragma unroll
            for (int kb = 0; kb < 4; ++kb)
                acc = __builtin_amdgcn_mfma_f32_16x16x32_bf16(afrag[kb], bp[kb * 64], acc, 0, 0, 0);
            const int n = nt * 16 + lane16;
            const float bias = b_out[n];
            #pragma unroll
            for (int r = 0; r < 4; ++r) {
                const int tl = w * 16 + quad * 4 + r;
                const size_t grow = batch_base + (size_t)(Y + (tl >> 3)) * 128 + (X + (tl & 7));
                __builtin_nontemporal_store(acc[r] + bias + 2.0f * qpre[nt][r],
                                            &out[grow * 128 + n]);
            }
        }
    }
}

extern "C" void kernel_launch(void* const* d_in, const int* in_sizes, int n_in,
                              void* d_out, int out_size, void* d_ws, size_t ws_size,
                              hipStream_t stream)
{
    // setup_inputs() dict order (all float32 per the reference):
    const float* query  = (const float*)d_in[0];
    const float* W_off  = (const float*)d_in[1];
    const float* b_off  = (const float*)d_in[2];
    const float* W_attn = (const float*)d_in[3];
    const float* b_attn = (const float*)d_in[4];
    const float* W_val  = (const float*)d_in[5];
    const float* b_val  = (const float*)d_in[6];
    const float* W_out  = (const float*)d_in[7];
    const float* b_out  = (const float*)d_in[8];
    float* out = (float*)d_out;

    u16* Wswz     = (u16*)d_ws;                      // 57 KB
    u16* Wout_swz = (u16*)((char*)d_ws + 28672 * 2); // 32 KB

    setup_kernel<<<176, 256, 0, stream>>>(W_val, W_off, W_attn, W_out, Wswz, Wout_swz);
    fused_kernel<<<1024, 256, 0, stream>>>(query, b_off, b_attn, b_val, b_out,
                                           Wswz, Wout_swz, out);
}

// Round 8
// 137.461 us; speedup vs baseline: 1.0391x; 1.0391x over previous
//
#include <hip/hip_runtime.h>

#define BS 4
#define NQ 16384

typedef unsigned short u16;
typedef unsigned int u32;
typedef unsigned char u8;
typedef __attribute__((ext_vector_type(8))) short bf16x8;   // 8 bf16 (4 VGPRs)
typedef __attribute__((ext_vector_type(4))) short bf16x4;
typedef __attribute__((ext_vector_type(4))) float f32x4;
typedef __attribute__((ext_vector_type(2))) float f32x2;

__device__ __forceinline__ float bf2f(u16 v) { return __uint_as_float(((u32)v) << 16); }
__device__ __forceinline__ u16 f2bf(float f) {           // RNE (setup only, cold)
    u32 u = __float_as_uint(f);
    return (u16)((u + 0x7fffu + ((u >> 16) & 1u)) >> 16);
}
// pack two f32 -> two bf16 (truncation) in ONE v_perm_b32
__device__ __forceinline__ u32 pk_trunc(float lo, float hi) {
    return __builtin_amdgcn_perm(__float_as_uint(hi), __float_as_uint(lo), 0x07060302u);
}

union ABu { bf16x8 v; u32 u[4]; };

// ---------------------------------------------------------------------------
// Setup: swizzle weights into MFMA fragment order (bf16, RNE).
// frag: f[j] = W[k = kb*32 + quad*8 + j][n = nt*16 + lane16], flat index
// (((nt*4+kb)*4+quad)*16 + lane16)*8 + j. Serves as B-frag (n=col) or as
// A-frag of W^T (m=col) — identical layout.
// ---------------------------------------------------------------------------
__global__ __launch_bounds__(256)
void setup_kernel(const float* __restrict__ W_val, const float* __restrict__ W_off,
                  const float* __restrict__ W_attn, const float* __restrict__ W_out,
                  u16* __restrict__ Wswz, u16* __restrict__ Wout_swz)
{
    const int i = blockIdx.x * 256 + threadIdx.x;
    if (i < 28672) {                       // proj [W_val | W_off | W_attn], 14 nt
        const int j = i & 7, lane = (i >> 3) & 15, quad = (i >> 7) & 3;
        const int kb = (i >> 9) & 3, nt = i >> 11;
        const int k = kb * 32 + quad * 8 + j;
        const int n = nt * 16 + lane;
        float v;
        if (n < 128)      v = W_val[k * 128 + n];
        else if (n < 192) v = W_off[k * 64 + (n - 128)];
        else              v = W_attn[k * 32 + (n - 192)];
        Wswz[i] = f2bf(v);
    } else if (i < 45056) {                // W_out, 8 nt
        const int i2 = i - 28672;
        const int j = i2 & 7, lane = (i2 >> 3) & 15, quad = (i2 >> 7) & 3;
        const int kb = (i2 >> 9) & 3, nt = i2 >> 11;
        const int k = kb * 32 + quad * 8 + j;
        const int n = nt * 16 + lane;
        Wout_swz[i2] = f2bf(W_out[k * 128 + n]);
    }
}

// ---------------------------------------------------------------------------
// Fused kernel (R6 structure + XCD swizzle; regular stores; 4 blocks/CU):
//   block = 8x8 token square, 12x12 fp8 value halo in LDS.
//   1a: off/attn proj, operand-swapped MFMA (D = [col][token]) -> scratch bf16
//   1b: value proj for 144 halo px (9 MFMA tiles), swapped (D = [dim][pixel]),
//       fp8-packed dword LDS stores
//   2a: off/attn -> regs, softmax over 4 pts     [barrier frees scratch]
//   2b: bilinear gather (1 ds_read_b128 + HW fp8 unpack per corner) -> s tile
//   2c: out MFMA (normal orientation) + bias + 2*query residual (L2-hit reload)
// XCD swizzle [measured R7: FETCH 53->25 MB]: bid&7 = XCD; each XCD owns a
// contiguous half-batch region (8x16 squares ~ 4 MB query) matching its L2.
// Nontemporal epilogue stores REGRESSED (WRITE 35->58 MB, R7) — regular stores.
// Batched phase-1 loads REGRESSED (VGPR 84, occupancy 21%, R7) — inline loads.
// C/D layout: col = lane&15, row = quad*4 + reg  [measured m89].
// ---------------------------------------------------------------------------
__global__ __launch_bounds__(256, 4)
void fused_kernel(const float* __restrict__ query,
                  const float* __restrict__ b_off, const float* __restrict__ b_attn,
                  const float* __restrict__ b_val, const float* __restrict__ b_out,
                  const u16* __restrict__ Wswz, const u16* __restrict__ Wout_swz,
                  float* __restrict__ out)
{
    __shared__ __align__(16) u8  vhalo[144 * 144];   // 20736 B, row stride 144 B
    __shared__ __align__(16) u16 scratch[64 * 136];  // 17408 B (off/attn, then s)

    const int tid = threadIdx.x;
    const int bid = blockIdx.x;
    // XCD-aware swizzle: xcd = bid&7 owns a contiguous 8x16-square half-batch
    const int xcd = bid & 7;
    const int ii  = bid >> 3;                 // 0..127 within the XCD's region
    const int b_  = xcd >> 1;                 // batch 0..3
    const int Y   = (((xcd & 1) << 3) | (ii >> 4)) << 3;   // 0..120
    const int X   = (ii & 15) << 3;

    const int w = tid >> 6, l = tid & 63;
    const int lane16 = l & 15, quad = l >> 4;
    const size_t batch_base = (size_t)b_ * NQ;

    const bf16x8* Wf  = (const bf16x8*)Wswz;
    const bf16x8* WfO = (const bf16x8*)Wout_swz;

    // ---------------- 1a: off/attn for own 16 tokens (swapped operands) -------
    {
        const int tl = w * 16 + lane16;              // own token 0..63 (lane = token)
        const float* qrow = query +
            (batch_base + (size_t)(Y + (tl >> 3)) * 128 + (X + (tl & 7))) * 128 + quad * 8;
        bf16x8 qfrag[4];
        #pragma unroll
        for (int kb = 0; kb < 4; ++kb) {
            f32x4 q0 = *(const f32x4*)(qrow + kb * 32);
            f32x4 q1 = *(const f32x4*)(qrow + kb * 32 + 4);
            ABu ab;
            ab.u[0] = pk_trunc(q0.x, q0.y); ab.u[1] = pk_trunc(q0.z, q0.w);
            ab.u[2] = pk_trunc(q1.x, q1.y); ab.u[3] = pk_trunc(q1.z, q1.w);
            qfrag[kb] = ab.v;
        }
        #pragma unroll
        for (int ntile = 0; ntile < 6; ++ntile) {
            const int nt = 8 + ntile;
            f32x4 acc = {0.f, 0.f, 0.f, 0.f};
            const bf16x8* wp = Wf + ((size_t)(nt * 4) * 4 + quad) * 16 + lane16;
            #pragma unroll
            for (int kb = 0; kb < 4; ++kb)
                acc = __builtin_amdgcn_mfma_f32_16x16x32_bf16(wp[kb * 64], qfrag[kb], acc, 0, 0, 0);
            const int c = ntile * 16 + quad * 4;     // col 0..95 (off 0..63, attn 64..95)
            const float4 bias = (ntile < 4) ? *(const float4*)&b_off[c]
                                            : *(const float4*)&b_attn[c - 64];
            uint2 pk;
            pk.x = pk_trunc(acc[0] + bias.x, acc[1] + bias.y);
            pk.y = pk_trunc(acc[2] + bias.z, acc[3] + bias.w);
            *(uint2*)&scratch[tl * 96 + c] = pk;
        }
    }

    // ---------------- 1b: fp8 value halo, 9 tiles of 16 pixels (swapped) ------
    #pragma unroll
    for (int i = 0; i < 3; ++i) {
        const int a = w + 4 * i;                     // tiles 0..8 over 4 waves
        if (a >= 9) break;
        const int hp = a * 16 + lane16;              // halo pixel 0..143 (lane = pixel)
        const int hy = hp / 12, hx = hp - hy * 12;
        const int gy = min(max(Y - 2 + hy, 0), 127);
        const int gx = min(max(X - 2 + hx, 0), 127);
        const float* qrow = query + (batch_base + (size_t)gy * 128 + gx) * 128 + quad * 8;
        bf16x8 qfrag[4];
        #pragma unroll
        for (int kb = 0; kb < 4; ++kb) {
            f32x4 q0 = *(const f32x4*)(qrow + kb * 32);
            f32x4 q1 = *(const f32x4*)(qrow + kb * 32 + 4);
            ABu ab;
            ab.u[0] = pk_trunc(q0.x, q0.y); ab.u[1] = pk_trunc(q0.z, q0.w);
            ab.u[2] = pk_trunc(q1.x, q1.y); ab.u[3] = pk_trunc(q1.z, q1.w);
            qfrag[kb] = ab.v;
        }
        #pragma unroll
        for (int mt = 0; mt < 8; ++mt) {             // 8 dim-tiles of W_val^T
            f32x4 acc = {0.f, 0.f, 0.f, 0.f};
            const bf16x8* wp = Wf + ((size_t)(mt * 4) * 4 + quad) * 16 + lane16;
            #pragma unroll
            for (int kb = 0; kb < 4; ++kb)
                acc = __builtin_amdgcn_mfma_f32_16x16x32_bf16(wp[kb * 64], qfrag[kb], acc, 0, 0, 0);
            const int d0 = mt * 16 + quad * 4;       // 4 consecutive dims of this pixel
            const float4 bias = *(const float4*)&b_val[d0];
            u32 pk = __builtin_amdgcn_cvt_pk_fp8_f32(acc[0] + bias.x, acc[1] + bias.y, 0, false);
            pk     = __builtin_amdgcn_cvt_pk_fp8_f32(acc[2] + bias.z, acc[3] + bias.w, pk, true);
            *(u32*)&vhalo[hp * 144 + d0] = pk;       // one dword store
        }
    }
    __syncthreads();

    // ---------------- 2a: off/attn -> regs (softmax over 4 pts) ---------------
    float aw[2][4], ox[2][4], oy[2][4];
    #pragma unroll
    for (int it = 0; it < 2; ++it) {
        const int item = it * 256 + tid;
        const int t = item >> 3, h = item & 7;
        bf16x8 ofr = *(const bf16x8*)&scratch[t * 96 + h * 8];
        bf16x4 atr = *(const bf16x4*)&scratch[t * 96 + 64 + h * 4];
        #pragma unroll
        for (int p = 0; p < 4; ++p) {
            ox[it][p] = bf2f((u16)ofr[2 * p]);
            oy[it][p] = bf2f((u16)ofr[2 * p + 1]);
        }
        const float l0 = bf2f((u16)atr[0]), l1 = bf2f((u16)atr[1]);
        const float l2 = bf2f((u16)atr[2]), l3 = bf2f((u16)atr[3]);
        const float m = fmaxf(fmaxf(l0, l1), fmaxf(l2, l3));
        const float e0 = __expf(l0 - m), e1 = __expf(l1 - m);
        const float e2 = __expf(l2 - m), e3 = __expf(l3 - m);
        const float inv = 1.0f / (e0 + e1 + e2 + e3);
        aw[it][0] = e0 * inv; aw[it][1] = e1 * inv;
        aw[it][2] = e2 * inv; aw[it][3] = e3 * inv;
    }
    __syncthreads();   // scratch becomes the s tile

    // ---------------- 2b: bilinear gather from fp8 halo -> s tile -------------
    #pragma unroll
    for (int it = 0; it < 2; ++it) {
        const int item = it * 256 + tid;
        const int t = item >> 3, h = item & 7;
        const int qx = X + (t & 7), qy = Y + (t >> 3);
        const float cx = (float)qx * (128.0f / 127.0f);
        const float cy = (float)qy * (128.0f / 127.0f);

        f32x2 acc2[8];
        #pragma unroll
        for (int d = 0; d < 8; ++d) acc2[d] = (f32x2){0.f, 0.f};

        #pragma unroll
        for (int p = 0; p < 4; ++p) {
            const float px = cx + ox[it][p] - 0.5f;
            const float py = cy + oy[it][p] - 0.5f;
            const float fx = floorf(px), fy = floorf(py);
            const float wx = px - fx, wy = py - fy;
            const int xi = (int)fx, yi = (int)fy;
            const float cw[4] = {(1.f - wx) * (1.f - wy), wx * (1.f - wy),
                                 (1.f - wx) * wy,         wx * wy};
            const int hx0 = min(max(xi - X + 2, 0), 11), hx1 = min(hx0 + 1, 11);
            const int hy0 = min(max(yi - Y + 2, 0), 11), hy1 = min(hy0 + 1, 11);
            const int cxs[4] = {hx0, hx1, hx0, hx1};
            const int cys[4] = {hy0, hy0, hy1, hy1};
            const int gxs[4] = {xi, xi + 1, xi, xi + 1};
            const int gys[4] = {yi, yi, yi + 1, yi + 1};
            #pragma unroll
            for (int c4 = 0; c4 < 4; ++c4) {
                const bool valid = (gxs[c4] >= 0) & (gxs[c4] < 128) &
                                   (gys[c4] >= 0) & (gys[c4] < 128);
                const float wgt = valid ? cw[c4] * aw[it][p] : 0.f;
                const f32x2 w2 = {wgt, wgt};
                const int hp = cys[c4] * 12 + cxs[c4];
                const int4 rv = *(const int4*)&vhalo[hp * 144 + h * 16];
                acc2[0] += w2 * __builtin_amdgcn_cvt_pk_f32_fp8(rv.x, false);
                acc2[1] += w2 * __builtin_amdgcn_cvt_pk_f32_fp8(rv.x, true);
                acc2[2] += w2 * __builtin_amdgcn_cvt_pk_f32_fp8(rv.y, false);
                acc2[3] += w2 * __builtin_amdgcn_cvt_pk_f32_fp8(rv.y, true);
                acc2[4] += w2 * __builtin_amdgcn_cvt_pk_f32_fp8(rv.z, false);
                acc2[5] += w2 * __builtin_amdgcn_cvt_pk_f32_fp8(rv.z, true);
                acc2[6] += w2 * __builtin_amdgcn_cvt_pk_f32_fp8(rv.w, false);
                acc2[7] += w2 * __builtin_amdgcn_cvt_pk_f32_fp8(rv.w, true);
            }
        }
        uint4 s0, s1;
        s0.x = pk_trunc(acc2[0][0], acc2[0][1]); s0.y = pk_trunc(acc2[1][0], acc2[1][1]);
        s0.z = pk_trunc(acc2[2][0], acc2[2][1]); s0.w = pk_trunc(acc2[3][0], acc2[3][1]);
        s1.x = pk_trunc(acc2[4][0], acc2[4][1]); s1.y = pk_trunc(acc2[5][0], acc2[5][1]);
        s1.z = pk_trunc(acc2[6][0], acc2[6][1]); s1.w = pk_trunc(acc2[7][0], acc2[7][1]);
        *(uint4*)&scratch[t * 136 + h * 16]     = s0;
        *(uint4*)&scratch[t * 136 + h * 16 + 8] = s1;
    }
    __syncthreads();

    // ---------------- 2c: out MFMA (normal orientation) + residual ------------
    {
        bf16x8 afrag[4];
        #pragma unroll
        for (int kb = 0; kb < 4; ++kb)
            afrag[kb] = *(const bf16x8*)&scratch[(w * 16 + lane16) * 136 + kb * 32 + quad * 8];

        #pragma unroll
        for (int nt = 0; nt < 8; ++nt) {
            f32x4 acc = {0.f, 0.f, 0.f, 0.f};
            const bf16x8* bp = WfO + ((size_t)(nt * 4) * 4 + quad) * 16 + lane16;
            #pragma unroll
            for (int kb = 0; kb < 4; ++kb)
                acc = __builtin_amdgcn_mfma_f32_16x16x32_bf16(afrag[kb], bp[kb * 64], acc, 0, 0, 0);
            const int n = nt * 16 + lane16;
            const float bias = b_out[n];
            #pragma unroll
            for (int r = 0; r < 4; ++r) {
                const int tl = w * 16 + quad * 4 + r;
                const size_t grow = batch_base + (size_t)(Y + (tl >> 3)) * 128 + (X + (tl & 7));
                const float q = query[grow * 128 + n];   // L2 hit (loaded in phase 1)
                out[grow * 128 + n] = acc[r] + bias + 2.0f * q;
            }
        }
    }
}

extern "C" void kernel_launch(void* const* d_in, const int* in_sizes, int n_in,
                              void* d_out, int out_size, void* d_ws, size_t ws_size,
                              hipStream_t stream)
{
    // setup_inputs() dict order (all float32 per the reference):
    const float* query  = (const float*)d_in[0];
    const float* W_off  = (const float*)d_in[1];
    const float* b_off  = (const float*)d_in[2];
    const float* W_attn = (const float*)d_in[3];
    const float* b_attn = (const float*)d_in[4];
    const float* W_val  = (const float*)d_in[5];
    const float* b_val  = (const float*)d_in[6];
    const float* W_out  = (const float*)d_in[7];
    const float* b_out  = (const float*)d_in[8];
    float* out = (float*)d_out;

    u16* Wswz     = (u16*)d_ws;                      // 57 KB
    u16* Wout_swz = (u16*)((char*)d_ws + 28672 * 2); // 32 KB

    setup_kernel<<<176, 256, 0, stream>>>(W_val, W_off, W_attn, W_out, Wswz, Wout_swz);
    fused_kernel<<<1024, 256, 0, stream>>>(query, b_off, b_attn, b_val, b_out,
                                           Wswz, Wout_swz, out);
}